// Round 1
// baseline (836.202 us; speedup 1.0000x reference)
//
#include <hip/hip_runtime.h>
#include <math.h>

#define NB 16384
#define LH 50
#define D  64

// One wave (64 lanes) per node b. lane = history slot (lanes 50..63 idle).
// Each lane holds all 64 outputs of each layer in registers; weight rows are
// wave-uniform -> scalar loads feeding v_fmac (SGPR operand), zero LDS traffic.
__global__ __launch_bounds__(256) void uv_agg_kernel(
    const int*   __restrict__ nodes,
    const int*   __restrict__ history_uv,
    const int*   __restrict__ history_r,
    const float* __restrict__ v2e,
    const float* __restrict__ u2e,
    const float* __restrict__ r2e,
    const float* __restrict__ w1,   // [128,64]
    const float* __restrict__ b1,   // [64]
    const float* __restrict__ w2,   // [64,64]
    const float* __restrict__ b2,   // [64]
    const float* __restrict__ wa1,  // [128,64]
    const float* __restrict__ ba1,  // [64]
    const float* __restrict__ wa2,  // [64,64]
    const float* __restrict__ ba2,  // [64]
    const float* __restrict__ wa3,  // [64]
    const float* __restrict__ ba3,  // [1]
    float*       __restrict__ out)  // [B,64]
{
    __shared__ float lds_c[4 * D];          // per-wave 64-float broadcast buffer
    const int lane = threadIdx.x & 63;
    const int wid  = threadIdx.x >> 6;
    const int b    = blockIdx.x * 4 + wid;

    // ---- per-wave uniform part of att1: c[d] = ba1[d] + sum_k u_k * wa1[64+k][d]
    // nodes[b] and the u row are wave-uniform -> scalar loads.
    {
        const int node = nodes[b];
        const float* __restrict__ urow = u2e + (size_t)node * D;
        float c = ba1[lane];
        #pragma unroll
        for (int k = 0; k < D; ++k)
            c = fmaf(urow[k], wa1[(D + k) * D + lane], c);
        lds_c[wid * D + lane] = c;
    }
    __syncthreads();

    // ---- per-lane token
    const bool act = lane < LH;
    const int iv = act ? history_uv[b * LH + lane] : 0;
    const int ir = act ? history_r [b * LH + lane] : 0;
    const float* __restrict__ xrow = v2e + (size_t)iv * D;
    const float* __restrict__ rrow = r2e + (size_t)ir * D;

    // ---- layer 1: h = relu(W1[0:64]^T e_uv + W1[64:128]^T e_r + b1)
    float h[D];
    #pragma unroll
    for (int d = 0; d < D; ++d) h[d] = b1[d];
    #pragma unroll 8
    for (int k = 0; k < D; ++k) {
        const float xk = xrow[k];
        const float* __restrict__ wr = w1 + k * D;
        #pragma unroll
        for (int d = 0; d < D; ++d) h[d] = fmaf(xk, wr[d], h[d]);
    }
    #pragma unroll 8
    for (int k = 0; k < D; ++k) {
        const float xk = rrow[k];
        const float* __restrict__ wr = w1 + (D + k) * D;
        #pragma unroll
        for (int d = 0; d < D; ++d) h[d] = fmaf(xk, wr[d], h[d]);
    }
    #pragma unroll
    for (int d = 0; d < D; ++d) h[d] = fmaxf(h[d], 0.f);

    // ---- layer 2: o = relu(W2^T h + b2)
    float o[D];
    #pragma unroll
    for (int d = 0; d < D; ++d) o[d] = b2[d];
    #pragma unroll
    for (int k = 0; k < D; ++k) {
        const float hk = h[k];
        const float* __restrict__ wr = w2 + k * D;
        #pragma unroll
        for (int d = 0; d < D; ++d) o[d] = fmaf(hk, wr[d], o[d]);
    }
    #pragma unroll
    for (int d = 0; d < D; ++d) o[d] = fmaxf(o[d], 0.f);

    // ---- att1: a1 = relu(c + Wa1[0:64]^T o)   (c already holds bias + u-half)
    float a1[D];
    #pragma unroll
    for (int d = 0; d < D; ++d) a1[d] = lds_c[wid * D + d];
    #pragma unroll
    for (int k = 0; k < D; ++k) {
        const float ok = o[k];
        const float* __restrict__ wr = wa1 + k * D;
        #pragma unroll
        for (int d = 0; d < D; ++d) a1[d] = fmaf(ok, wr[d], a1[d]);
    }
    #pragma unroll
    for (int d = 0; d < D; ++d) a1[d] = fmaxf(a1[d], 0.f);

    // ---- att2 (+relu) and att3 logit
    float a2[D];
    #pragma unroll
    for (int d = 0; d < D; ++d) a2[d] = ba2[d];
    #pragma unroll
    for (int k = 0; k < D; ++k) {
        const float ak = a1[k];
        const float* __restrict__ wr = wa2 + k * D;
        #pragma unroll
        for (int d = 0; d < D; ++d) a2[d] = fmaf(ak, wr[d], a2[d]);
    }
    float lg = ba3[0];
    #pragma unroll
    for (int d = 0; d < D; ++d) lg = fmaf(fmaxf(a2[d], 0.f), wa3[d], lg);
    if (!act) lg = -1e30f;

    // ---- softmax over history slots (wave-level)
    float m = lg;
    #pragma unroll
    for (int off = 32; off >= 1; off >>= 1)
        m = fmaxf(m, __shfl_xor(m, off, 64));
    const float e = __expf(lg - m);   // idle lanes: exp(-huge) = 0
    float s = e;
    #pragma unroll
    for (int off = 32; off >= 1; off >>= 1)
        s += __shfl_xor(s, off, 64);
    const float att = e / s;

    // ---- out[b,:] = sum_l att_l * o_l : 64-component butterfly reduction
    float r[D];
    #pragma unroll
    for (int d = 0; d < D; ++d) r[d] = att * o[d];
    #pragma unroll
    for (int off = 32; off >= 1; off >>= 1) {
        #pragma unroll
        for (int d = 0; d < D; ++d) r[d] += __shfl_xor(r[d], off, 64);
    }

    // all lanes now hold the identical output row; deposit once, store coalesced
    if (lane == 0) {
        #pragma unroll
        for (int d = 0; d < D; ++d) lds_c[wid * D + d] = r[d];
    }
    __syncthreads();
    out[(size_t)b * D + lane] = lds_c[wid * D + lane];
}

extern "C" void kernel_launch(void* const* d_in, const int* in_sizes, int n_in,
                              void* d_out, int out_size, void* d_ws, size_t ws_size,
                              hipStream_t stream) {
    const int*   nodes      = (const int*)  d_in[0];
    const int*   history_uv = (const int*)  d_in[1];
    const int*   history_r  = (const int*)  d_in[2];
    const float* v2e        = (const float*)d_in[3];
    const float* u2e        = (const float*)d_in[4];
    const float* r2e        = (const float*)d_in[5];
    const float* w1         = (const float*)d_in[6];
    const float* b1         = (const float*)d_in[7];
    const float* w2         = (const float*)d_in[8];
    const float* b2         = (const float*)d_in[9];
    const float* wa1        = (const float*)d_in[10];
    const float* ba1        = (const float*)d_in[11];
    const float* wa2        = (const float*)d_in[12];
    const float* ba2        = (const float*)d_in[13];
    const float* wa3        = (const float*)d_in[14];
    const float* ba3        = (const float*)d_in[15];
    float* out = (float*)d_out;

    uv_agg_kernel<<<NB / 4, 256, 0, stream>>>(
        nodes, history_uv, history_r, v2e, u2e, r2e,
        w1, b1, w2, b2, wa1, ba1, wa2, ba2, wa3, ba3, out);
}